// Round 4
// baseline (587.218 us; speedup 1.0000x reference)
//
#include <hip/hip_runtime.h>
#include <math.h>
#include <stdint.h>

#define BATCH 64
#define T 256
#define NF 64
#define H 128
#define H4 512                    // 4*H
#define HP1 129
#define WF_STRIDE (HP1 * H4)      // 66048 floats per feature
#define FEATS (NF * H + H)        // 8320
#define NTH 1024                  // scan kernel threads (16 waves)

#define CHUNK_BYTES 32768         // 32 k-rows * 512 cols * 2B fp16
#define PACK_U4_PER_F 8192        // 4 cc * 2 i * 1024 tid
#define PACK_BYTES (64u * PACK_U4_PER_F * 16u)     // 8 MB
#define HDR_BYTES  (64u * 1024u * 2u)              // fp16 wx/bias header, 128 KB
#define WS_NEED ((size_t)HDR_BYTES + (size_t)PACK_BYTES)   // 8519680 (= proven ws size)

typedef _Float16 half2_t __attribute__((ext_vector_type(2)));

__device__ __forceinline__ float sigmoidf_(float x) {
    return 1.0f / (1.0f + __expf(-x));
}

__device__ __forceinline__ float tanhf_(float x) {
    float ax = fabsf(x);
    float e = __expf(2.0f * ax);              // inf for large ax -> r = 1
    float r = 1.0f - 2.0f / (e + 1.0f);
    return copysignf(r, x);
}

__device__ __forceinline__ float fdot2_(half2_t a, half2_t b, float c) {
#if defined(__has_builtin)
#if __has_builtin(__builtin_amdgcn_fdot2)
    return __builtin_amdgcn_fdot2(a, b, c, false);
#else
    return fmaf((float)a.x, (float)b.x, fmaf((float)a.y, (float)b.y, c));
#endif
#else
    return fmaf((float)a.x, (float)b.x, fmaf((float)a.y, (float)b.y, c));
#endif
}

// ---- async global->LDS DMA (size must be literal) ----
#if defined(__has_builtin)
#if __has_builtin(__builtin_amdgcn_global_load_lds)
#define HAVE_GLL 1
#endif
#endif

__device__ __forceinline__ void dma16(const void* g, uint32_t lds_byte) {
#ifdef HAVE_GLL
    __builtin_amdgcn_global_load_lds(
        (const __attribute__((address_space(1))) void*)g,
        (__attribute__((address_space(3))) void*)(uintptr_t)lds_byte,
        16, 0, 0);
#endif
}
__device__ __forceinline__ void dma4(const void* g, uint32_t lds_byte) {
#ifdef HAVE_GLL
    __builtin_amdgcn_global_load_lds(
        (const __attribute__((address_space(1))) void*)g,
        (__attribute__((address_space(3))) void*)(uintptr_t)lds_byte,
        4, 0, 0);
#endif
}

#define WAITV(N) do { asm volatile("s_waitcnt vmcnt(" #N ")" ::: "memory"); \
                      __builtin_amdgcn_sched_barrier(0); } while (0)
#define BARRIER() do { asm volatile("s_waitcnt lgkmcnt(0)" ::: "memory"); \
                       __builtin_amdgcn_s_barrier(); \
                       asm volatile("" ::: "memory"); } while (0)

// ===================== repack: W_lin h-rows -> fp16 chunked DMA layout ======
// pack[((f*4 + cc)*2 + i)*1024 + tid] = uint4 of 4 half2, tid: kh=tid>>9, c=tid&511
//   k0 = cc*32 + kh*16 + i*8 ; h2[r] = ( W[f][1+k0+2r][c], W[f][2+k0+2r][c] )
__global__ __launch_bounds__(256)
void repack_kernel(const float* __restrict__ W_lin, uint4* __restrict__ pack) {
    const int lin = blockIdx.x * 256 + threadIdx.x;     // 0..524287
    const int f   = lin >> 13;
    const int idx = lin & 8191;
    const int tid = idx & 1023;
    const int i   = (idx >> 10) & 1;
    const int cc  = idx >> 11;
    const int kh  = tid >> 9;
    const int c   = tid & 511;
    const int k0  = cc * 32 + kh * 16 + i * 8;
    const float* src = W_lin + (size_t)f * WF_STRIDE + (size_t)(1 + k0) * H4 + c;
    half2_t h[4];
    #pragma unroll
    for (int r = 0; r < 4; ++r) {
        h[r].x = (_Float16)src[(2 * r) * H4];
        h[r].y = (_Float16)src[(2 * r + 1) * H4];
    }
    pack[lin] = *(uint4*)h;
}

// hdr[f*1024 + t] (fp16): t<512 -> W_lin[f][0][t] (x-row); t>=512 -> b_lin[f][t-512]
__global__ __launch_bounds__(256)
void hdr_kernel(const float* __restrict__ W_lin, const float* __restrict__ b_lin,
                _Float16* __restrict__ hdr) {
    const int lin = blockIdx.x * 256 + threadIdx.x;     // 0..65535
    const int f = lin >> 10, t = lin & 1023;
    const float v = (t < 512) ? W_lin[(size_t)f * WF_STRIDE + t]
                              : b_lin[f * H4 + (t & 511)];
    hdr[lin] = (_Float16)v;
}

// ===================== main scan: LDS DMA ring, counted vmcnt ======
// 4 chunks/step through a 3-buffer LDS ring, staged 2 chunks ahead via
// global_load_lds. Each wave stages & reads only its own 64-lane slice ->
// weight readiness is per-wave vmcnt only (no barrier). No compiler global
// loads in the loop (bias/x-row via fp16 hdr DMA), so vmcnt counts are exact.
__global__ __launch_bounds__(NTH, 4)
void lstm_scan_dma(const float* __restrict__ X,
                   const int* __restrict__ lengths,
                   const float* __restrict__ W_dec,
                   const float* __restrict__ b_dec,
                   const float* __restrict__ W_out,
                   const float* __restrict__ b_out,
                   const uint4* __restrict__ pack,
                   const _Float16* __restrict__ hdr,
                   float* __restrict__ out)
{
    __shared__ __align__(16) char s_wb[3 * CHUNK_BYTES];   // 96 KB weight ring
    __shared__ __align__(16) char s_hdr[2 * 4096];         // wx/bias staging (dbuf)
    __shared__ __align__(16) char s_inp2[64 * 4];          // 64 half2: decayed hidden
    __shared__ float s_ht[NF * H];                         // fp32 h table
    __shared__ float s_part[2][H4];
    __shared__ float s_X[4 * T];
    __shared__ float s_wdec[NF];
    __shared__ float s_bdec[NF];
    __shared__ float s_cfin[H];
    __shared__ float s_red[32];

    const int tid = threadIdx.x;
    const int b   = blockIdx.x;
    const int wv  = tid >> 6;
    const int kh  = tid >> 9;                 // K half (0/1)
    const int c   = tid & 511;                // gate column

    const float* Xb = X + b * 4 * T;
    const int len = lengths[b];

    for (int i = tid; i < NF * H; i += NTH) s_ht[i] = 0.0f;
    for (int i = tid; i < 4 * T; i += NTH) s_X[i] = Xb[i];
    if (tid < NF) { s_wdec[tid] = W_dec[tid]; s_bdec[tid] = b_dec[tid]; }
    if (tid < H) ((_Float16*)s_inp2)[tid] = (_Float16)0.0f;
    __syncthreads();                           // full drain before pipeline starts

    // wave-uniform staged-LDS bases (SGPR) + per-thread read base
    const uint32_t wb_base  = (uint32_t)(uintptr_t)s_wb;
    const uint32_t hd_base  = (uint32_t)(uintptr_t)s_hdr;
    const uint32_t wb_st = __builtin_amdgcn_readfirstlane(wb_base + wv * 1024);
    const uint32_t hd_st = __builtin_amdgcn_readfirstlane(hd_base + wv * 256);
    const uint32_t wb_rd = wb_base + tid * 16;

    float c_t = 0.0f, acc = 0.0f, cnt = 0.0f;

    #define STAGE_W(fv, ccv, OFF) do {                                          \
        const uint4* gp = pack + (size_t)(((fv) * 4 + (ccv)) * 2) * 1024 + tid; \
        dma16(gp,        wb_st + (OFF));                                        \
        dma16(gp + 1024, wb_st + (OFF) + 16384);                                \
    } while (0)

    #define STAGE_H(sv) do {                                                    \
        const int ss = ((sv) < T) ? (sv) : (T - 1);                             \
        const _Float16* gh = hdr + (int)s_X[T + ss] * 1024 + (tid & 1022);      \
        dma4(gh, hd_st + (((sv) & 1) ? 4096 : 0));                              \
    } while (0)

    #define CHUNK_C(ccv, OFF) do {                                              \
        uint4 w0, w1;                                                           \
        const uint32_t ra = wb_rd + (OFF);                                      \
        asm volatile("ds_read_b128 %0, %2 offset:0\n\t"                         \
                     "ds_read_b128 %1, %2 offset:16384"                         \
                     : "=&v"(w0), "=&v"(w1) : "v"(ra) : "memory");              \
        const uint4 iv0 = *(const uint4*)(s_inp2 + ((ccv) * 16 + kh * 8) * 4);  \
        const uint4 iv1 = *(const uint4*)(s_inp2 + ((ccv) * 16 + kh * 8 + 4) * 4); \
        asm volatile("s_waitcnt lgkmcnt(0)" ::: "memory");                      \
        __builtin_amdgcn_sched_barrier(0);                                      \
        union { uint4 u; half2_t h[4]; } cw0, cw1, ci0, ci1;                    \
        cw0.u = w0; cw1.u = w1; ci0.u = iv0; ci1.u = iv1;                       \
        a0 = fdot2_(cw0.h[0], ci0.h[0], a0); a1 = fdot2_(cw0.h[1], ci0.h[1], a1); \
        a0 = fdot2_(cw0.h[2], ci0.h[2], a0); a1 = fdot2_(cw0.h[3], ci0.h[3], a1); \
        a0 = fdot2_(cw1.h[0], ci1.h[0], a0); a1 = fdot2_(cw1.h[1], ci1.h[1], a1); \
        a0 = fdot2_(cw1.h[2], ci1.h[2], a0); a1 = fdot2_(cw1.h[3], ci1.h[3], a1); \
    } while (0)

    // prologue: stage step-0 chunks 0,1 + hdr(0)  -> 5 outstanding
    {
        const int m0 = (int)s_X[T];
        STAGE_W(m0, 0, 0);
        STAGE_W(m0, 1, CHUNK_BYTES);
        STAGE_H(0);
    }

    #define STEP(O0, O1, O2) {                                                  \
        const int   mj  = (int)s_X[T + j];                                      \
        const float xj  = s_X[2 * T + j];                                       \
        const int   jn  = (j + 1 < T) ? (j + 1) : (T - 1);                      \
        const int   mjn = (int)s_X[T + jn];                                     \
        float a0 = 0.0f, a1 = 0.0f;                                             \
        STAGE_W(mj, 2, O2);  STAGE_H(j + 1); WAITV(5); CHUNK_C(0, O0);          \
        STAGE_W(mj, 3, O0);                  WAITV(5); CHUNK_C(1, O1);          \
        STAGE_W(mjn, 0, O1);                 WAITV(5); CHUNK_C(2, O2);          \
        STAGE_W(mjn, 1, O2);                 WAITV(4); CHUNK_C(3, O0);          \
        float a = a0 + a1;                                                      \
        {                                                                       \
            const float hv = (float)*(const _Float16*)(s_hdr                    \
                + ((j & 1) ? 4096 : 0) + tid * 4 + (tid & 1) * 2);              \
            a = kh ? (a + hv) : fmaf(xj, hv, a);                                \
        }                                                                       \
        s_part[kh][c] = a;                                                      \
        BARRIER();  /* partials ready */                                        \
        if (tid < H) {                                                          \
            const int h = tid;                                                  \
            const float gi = s_part[0][h]         + s_part[1][h];               \
            const float gf = s_part[0][H + h]     + s_part[1][H + h];           \
            const float go = s_part[0][2 * H + h] + s_part[1][2 * H + h];       \
            const float gc = s_part[0][3 * H + h] + s_part[1][3 * H + h];       \
            const float c_cand = sigmoidf_(gf) * c_t + sigmoidf_(gi) * tanhf_(gc); \
            const float h_row  = sigmoidf_(go) * tanhf_(c_cand);                \
            s_ht[mj * H + h] = h_row;                                           \
            acc += c_cand;                                                      \
            cnt += 1.0f;                                                        \
            const float tj = s_X[j];                                            \
            const float tn = (j < T - 1) ? s_X[j + 1] : (tj + 1.0f);            \
            const bool boundary = (j == len - 1) || (tn != tj);                 \
            if (boundary) { c_t = acc / fmaxf(cnt, 1.0f); acc = 0.0f; cnt = 0.0f; } \
            const float dn  = s_X[3 * T + jn];                                  \
            const float dmn = fmaf(s_wdec[mjn], dn, s_bdec[mjn]);               \
            const float den = __expf(-fmaxf(0.0f, dmn));                        \
            const float hv2 = (mjn == mj) ? h_row : s_ht[mjn * H + h];          \
            ((_Float16*)s_inp2)[h] = (_Float16)(den * hv2);                     \
        }                                                                       \
        BARRIER();  /* s_inp2 + h_t ready */                                    \
    }

    int j = 0;
    for (;;) {
        STEP(0, CHUNK_BYTES, 2 * CHUNK_BYTES); ++j; if (j >= len) break;
        STEP(CHUNK_BYTES, 2 * CHUNK_BYTES, 0); ++j; if (j >= len) break;
        STEP(2 * CHUNK_BYTES, 0, CHUNK_BYTES); ++j; if (j >= len) break;
    }
    #undef STEP
    #undef CHUNK_C
    #undef STAGE_W
    #undef STAGE_H

    asm volatile("s_waitcnt vmcnt(0) lgkmcnt(0)" ::: "memory");
    __syncthreads();

    // ---- epilogue ----
    if (tid < H) s_cfin[tid] = c_t;
    __syncthreads();

    float z0 = 0.0f, z1 = 0.0f;
    for (int i = tid; i < FEATS; i += NTH) {
        const float f = (i < H) ? s_cfin[i] : s_ht[i - H];
        const float2 w = *(const float2*)(W_out + 2 * i);
        z0 = fmaf(f, w.x, z0);
        z1 = fmaf(f, w.y, z1);
    }
    #pragma unroll
    for (int off = 32; off > 0; off >>= 1) {
        z0 += __shfl_down(z0, off, 64);
        z1 += __shfl_down(z1, off, 64);
    }
    const int wave = tid >> 6, lane = tid & 63;
    if (lane == 0) { s_red[2 * wave] = z0; s_red[2 * wave + 1] = z1; }
    __syncthreads();
    if (tid == 0) {
        float a0 = b_out[0], a1 = b_out[1];
        #pragma unroll
        for (int w = 0; w < 16; ++w) { a0 += s_red[2 * w]; a1 += s_red[2 * w + 1]; }
        const float mx = fmaxf(a0, a1);
        const float e0 = __expf(a0 - mx), e1 = __expf(a1 - mx);
        const float inv = 1.0f / (e0 + e1);
        out[2 * b]     = e0 * inv;
        out[2 * b + 1] = e1 * inv;
    }
}

// ---------------- fp32 fallback (no-workspace path) ----------------
#define NTHREADS 512
__global__ __launch_bounds__(NTHREADS)
void lstm_scan_kernel(const float* __restrict__ X,
                      const int* __restrict__ lengths,
                      const float* __restrict__ W_lin,
                      const float* __restrict__ b_lin,
                      const float* __restrict__ W_dec,
                      const float* __restrict__ b_dec,
                      const float* __restrict__ W_out,
                      const float* __restrict__ b_out,
                      float* __restrict__ out)
{
    __shared__ float s_feats[FEATS];
    __shared__ float s_inp[H];
    __shared__ float s_part[4][H4];
    __shared__ float s_X[4 * T];
    __shared__ float s_wdec[NF];
    __shared__ float s_bdec[NF];
    __shared__ float s_red[16];

    float* s_ct = s_feats;
    float* s_ht = s_feats + H;

    const int tid = threadIdx.x;
    const int b   = blockIdx.x;
    const int g4  = tid & 127;
    const int kq  = tid >> 7;

    const float* Xb = X + b * 4 * T;
    const int len = lengths[b];

    for (int i = tid; i < NF * H; i += NTHREADS) s_ht[i] = 0.0f;
    for (int i = tid; i < 4 * T; i += NTHREADS) s_X[i] = Xb[i];
    if (tid < NF) { s_wdec[tid] = W_dec[tid]; s_bdec[tid] = b_dec[tid]; }
    __syncthreads();

    float c_t = 0.0f, acc = 0.0f, cnt = 0.0f;

    for (int j = 0; j < len; ++j) {
        const int   mj = (int)s_X[T + j];
        const float xj = s_X[2 * T + j];
        const float* Wf = W_lin + mj * WF_STRIDE;

        float bl0, bl1, bl2, bl3;
        if (tid < H) {
            const float dj    = s_X[3 * T + j];
            const float dm    = fmaf(s_wdec[mj], dj, s_bdec[mj]);
            const float decay = __expf(-fmaxf(0.0f, dm));
            s_inp[tid] = decay * s_ht[mj * H + tid];
            const int m4 = mj * H4;
            bl0 = b_lin[m4 + tid];
            bl1 = b_lin[m4 + H + tid];
            bl2 = b_lin[m4 + 2 * H + tid];
            bl3 = b_lin[m4 + 3 * H + tid];
        }
        __syncthreads();

        float4 a4 = make_float4(0.0f, 0.0f, 0.0f, 0.0f);
        {
            const float*  wr  = Wf + (1 + kq * 32) * H4 + 4 * g4;
            const float4* ivp = (const float4*)(s_inp + kq * 32);
            #pragma unroll
            for (int cc = 0; cc < 8; ++cc) {
                const float4 v = ivp[cc];
                const float* wrc = wr + (4 * cc) * H4;
                const float4 w0 = *(const float4*)(wrc);
                const float4 w1 = *(const float4*)(wrc + H4);
                const float4 w2 = *(const float4*)(wrc + 2 * H4);
                const float4 w3 = *(const float4*)(wrc + 3 * H4);
                a4.x = fmaf(v.x, w0.x, a4.x); a4.y = fmaf(v.x, w0.y, a4.y);
                a4.z = fmaf(v.x, w0.z, a4.z); a4.w = fmaf(v.x, w0.w, a4.w);
                a4.x = fmaf(v.y, w1.x, a4.x); a4.y = fmaf(v.y, w1.y, a4.y);
                a4.z = fmaf(v.y, w1.z, a4.z); a4.w = fmaf(v.y, w1.w, a4.w);
                a4.x = fmaf(v.z, w2.x, a4.x); a4.y = fmaf(v.z, w2.y, a4.y);
                a4.z = fmaf(v.z, w2.z, a4.z); a4.w = fmaf(v.z, w2.w, a4.w);
                a4.x = fmaf(v.w, w3.x, a4.x); a4.y = fmaf(v.w, w3.y, a4.y);
                a4.z = fmaf(v.w, w3.z, a4.z); a4.w = fmaf(v.w, w3.w, a4.w);
            }
        }
        if (kq == 0) {
            const float4 w = *(const float4*)(Wf + 4 * g4);
            a4.x = fmaf(xj, w.x, a4.x); a4.y = fmaf(xj, w.y, a4.y);
            a4.z = fmaf(xj, w.z, a4.z); a4.w = fmaf(xj, w.w, a4.w);
        }
        *(float4*)(&s_part[kq][4 * g4]) = a4;
        __syncthreads();

        if (tid < H) {
            const int h = tid;
            const float gi = s_part[0][h]         + s_part[1][h]         + s_part[2][h]         + s_part[3][h]         + bl0;
            const float gf = s_part[0][H + h]     + s_part[1][H + h]     + s_part[2][H + h]     + s_part[3][H + h]     + bl1;
            const float go = s_part[0][2*H + h]   + s_part[1][2*H + h]   + s_part[2][2*H + h]   + s_part[3][2*H + h]   + bl2;
            const float gc = s_part[0][3*H + h]   + s_part[1][3*H + h]   + s_part[2][3*H + h]   + s_part[3][3*H + h]   + bl3;

            const float c_cand = sigmoidf_(gf) * c_t + sigmoidf_(gi) * tanhf_(gc);
            const float h_row  = sigmoidf_(go) * tanhf_(c_cand);
            s_ht[mj * H + h] = h_row;
            acc += c_cand;
            cnt += 1.0f;

            const float tj = s_X[j];
            const float tn = (j < T - 1) ? s_X[j + 1] : (tj + 1.0f);
            const bool boundary = (j == len - 1) || (tn != tj);
            if (boundary) { c_t = acc / fmaxf(cnt, 1.0f); acc = 0.0f; cnt = 0.0f; }
        }
        __syncthreads();
    }

    if (tid < H) s_ct[tid] = c_t;
    __syncthreads();

    float z0 = 0.0f, z1 = 0.0f;
    for (int i = tid; i < FEATS; i += NTHREADS) {
        const float f = s_feats[i];
        const float2 w = *(const float2*)(W_out + 2 * i);
        z0 = fmaf(f, w.x, z0);
        z1 = fmaf(f, w.y, z1);
    }
    #pragma unroll
    for (int off = 32; off > 0; off >>= 1) {
        z0 += __shfl_down(z0, off, 64);
        z1 += __shfl_down(z1, off, 64);
    }
    const int wave = tid >> 6, lane = tid & 63;
    if (lane == 0) { s_red[2 * wave] = z0; s_red[2 * wave + 1] = z1; }
    __syncthreads();
    if (tid == 0) {
        float a0 = b_out[0], a1 = b_out[1];
        #pragma unroll
        for (int w = 0; w < 8; ++w) { a0 += s_red[2 * w]; a1 += s_red[2 * w + 1]; }
        const float mx = fmaxf(a0, a1);
        const float e0 = __expf(a0 - mx), e1 = __expf(a1 - mx);
        const float inv = 1.0f / (e0 + e1);
        out[2 * b]     = e0 * inv;
        out[2 * b + 1] = e1 * inv;
    }
}

extern "C" void kernel_launch(void* const* d_in, const int* in_sizes, int n_in,
                              void* d_out, int out_size, void* d_ws, size_t ws_size,
                              hipStream_t stream) {
    const float* X      = (const float*)d_in[0];
    const int*   lens   = (const int*)d_in[1];
    const float* W_lin  = (const float*)d_in[2];
    const float* b_lin  = (const float*)d_in[3];
    const float* W_dec  = (const float*)d_in[4];
    const float* b_dec  = (const float*)d_in[5];
    const float* W_out  = (const float*)d_in[6];
    const float* b_out  = (const float*)d_in[7];
    float* out = (float*)d_out;

    if (ws_size >= WS_NEED) {
        _Float16* hdr = (_Float16*)d_ws;
        uint4* pack = (uint4*)((char*)d_ws + HDR_BYTES);
        hipLaunchKernelGGL(repack_kernel, dim3(2048), dim3(256), 0, stream, W_lin, pack);
        hipLaunchKernelGGL(hdr_kernel, dim3(256), dim3(256), 0, stream, W_lin, b_lin, hdr);
        hipLaunchKernelGGL(lstm_scan_dma, dim3(BATCH), dim3(NTH), 0, stream,
                           X, lens, W_dec, b_dec, W_out, b_out, pack, hdr, out);
    } else {
        hipLaunchKernelGGL(lstm_scan_kernel, dim3(BATCH), dim3(NTHREADS), 0, stream,
                           X, lens, W_lin, b_lin, W_dec, b_dec, W_out, b_out, out);
    }
}

// Round 6
// 465.675 us; speedup vs baseline: 1.2610x; 1.2610x over previous
//
#include <hip/hip_runtime.h>
#include <math.h>
#include <stdint.h>

#define BATCH 64
#define T 256
#define NF 64
#define H 128
#define H4 512                    // 4*H
#define HP1 129
#define WF_STRIDE (HP1 * H4)      // 66048 floats per feature
#define FEATS (NF * H + H)        // 8320
#define NTH 1024                  // scan kernel threads (16 waves)

// fp8 pack: per feature 64 KB = ((f*2+h)*2 + q)*1024 + tid  uint4 entries
#define PACK8_U4 (64 * 2 * 2 * 1024)                 // 262144 uint4
#define PACK8_BYTES ((size_t)PACK8_U4 * 16u)         // 4 MB

typedef _Float16 half2_t __attribute__((ext_vector_type(2)));
typedef float    vf2     __attribute__((ext_vector_type(2)));

__device__ __forceinline__ float sigmoidf_(float x) {
    return 1.0f / (1.0f + __expf(-x));
}

__device__ __forceinline__ float tanhf_(float x) {
    float ax = fabsf(x);
    float e = __expf(2.0f * ax);              // inf for large ax -> r = 1
    float r = 1.0f - 2.0f / (e + 1.0f);
    return copysignf(r, x);
}

__device__ __forceinline__ float fdot2_(half2_t a, half2_t b, float c) {
#if defined(__has_builtin)
#if __has_builtin(__builtin_amdgcn_fdot2)
    return __builtin_amdgcn_fdot2(a, b, c, false);
#else
    return fmaf((float)a.x, (float)b.x, fmaf((float)a.y, (float)b.y, c));
#endif
#else
    return fmaf((float)a.x, (float)b.x, fmaf((float)a.y, (float)b.y, c));
#endif
}

// decode 2 fp8 bytes (lo/hi pair of a dword) -> half2 (exact: fp8 subset of fp16)
// HI must be a compile-time constant for the builtin.
template<bool HI>
__device__ __forceinline__ half2_t dec8(unsigned u) {
    vf2 f = __builtin_amdgcn_cvt_pk_f32_fp8(u, HI);
    return (half2_t)__builtin_amdgcn_cvt_pkrtz(f[0], f[1]);
}

// ===================== repack: W_lin h-rows -> fp8 (x4096) =====================
// byte layout: pack[((f*2+h)*2+q)*1024 + tid], tid: kh=tid>>9, c=tid&511.
// byte r of dword w of the uint4 <-> k = h*64 + kh*32 + q*16 + 4w + r,
// value = fp8_e4m3( W_lin[f][1+k][c] * 4096 )
__global__ __launch_bounds__(256)
void repack8_kernel(const float* __restrict__ W_lin, uint4* __restrict__ pack) {
    const int lin = blockIdx.x * 256 + threadIdx.x;   // 0..262143
    const int tid = lin & 1023;
    const int q   = (lin >> 10) & 1;
    const int h   = (lin >> 11) & 1;
    const int f   = lin >> 12;
    const int kh  = tid >> 9;
    const int cc  = tid & 511;
    const int k0  = h * 64 + kh * 32 + q * 16;
    const float* src = W_lin + (size_t)f * WF_STRIDE + (size_t)(1 + k0) * H4 + cc;
    unsigned u[4];
    #pragma unroll
    for (int w = 0; w < 4; ++w) {
        const float v0 = src[(4 * w + 0) * H4] * 4096.0f;
        const float v1 = src[(4 * w + 1) * H4] * 4096.0f;
        const float v2 = src[(4 * w + 2) * H4] * 4096.0f;
        const float v3 = src[(4 * w + 3) * H4] * 4096.0f;
        unsigned r = 0;
        r = __builtin_amdgcn_cvt_pk_fp8_f32(v0, v1, r, false);
        r = __builtin_amdgcn_cvt_pk_fp8_f32(v2, v3, r, true);
        u[w] = r;
    }
    uint4 o; o.x = u[0]; o.y = u[1]; o.z = u[2]; o.w = u[3];
    pack[lin] = o;
}

// ===================== main scan: fp8 weights, register prefetch ===============
// Per thread per step: 4 uint4 of fp8 weights (64 k-bytes). half1(j) loaded and
// consumed in-step; half0(j+1) + bias + x-row prefetched one step ahead in
// registers (only ~13 VGPRs cross-barrier -> no AGPR staging pressure).
// Stream/step = 64 KB (vs 128 KB fp16): direct attack on the measured
// ~32 B/cy/CU load-bandwidth ceiling that all prior rounds sat at.
__global__ __launch_bounds__(NTH, 4)
void lstm_scan_fp8_kernel(const float* __restrict__ X,
                          const int* __restrict__ lengths,
                          const float* __restrict__ W_lin,
                          const float* __restrict__ b_lin,
                          const float* __restrict__ W_dec,
                          const float* __restrict__ b_dec,
                          const float* __restrict__ W_out,
                          const float* __restrict__ b_out,
                          const uint4* __restrict__ pack,
                          float* __restrict__ out)
{
    __shared__ float s_feats[FEATS];          // [0,H)=c_t, [H,..)=h_t row-major
    __shared__ half2_t s_inp2[H / 2];         // decayed hidden row, fp16 pairs
    __shared__ float s_part[2][H4];           // K-half matvec partials
    __shared__ float s_X[4 * T];
    __shared__ float s_wdec[NF];
    __shared__ float s_bdec[NF];
    __shared__ float s_red[32];

    float* s_ct = s_feats;
    float* s_ht = s_feats + H;

    const int tid = threadIdx.x;
    const int b   = blockIdx.x;
    const int c   = tid & 511;                // gate column
    const int kh  = tid >> 9;                 // K half (0/1), wave-uniform

    const float* Xb = X + b * 4 * T;
    const int len = lengths[b];

    for (int i = tid; i < NF * H; i += NTH) s_ht[i] = 0.0f;
    for (int i = tid; i < 4 * T; i += NTH) s_X[i] = Xb[i];
    if (tid < NF) { s_wdec[tid] = W_dec[tid]; s_bdec[tid] = b_dec[tid]; }
    if (tid < H / 2) { half2_t z; z.x = (_Float16)0.0f; z.y = (_Float16)0.0f; s_inp2[tid] = z; }
    __syncthreads();

    float c_t = 0.0f, acc = 0.0f, cnt = 0.0f;

    // dot of one weight-uint4 (16 fp8 k's) against input half2s at IB (half2 idx)
    #define DOTU4(W, IB) do {                                                   \
        const half2_t* ip = ((const half2_t*)s_inp2) + (IB);                    \
        union { uint4 u; half2_t h[4]; } I0, I1;                                \
        I0.u = *(const uint4*)(ip);                                             \
        I1.u = *(const uint4*)(ip + 4);                                         \
        a = fdot2_(dec8<false>(W.x), I0.h[0], a);                               \
        a = fdot2_(dec8<true >(W.x), I0.h[1], a);                               \
        a = fdot2_(dec8<false>(W.y), I0.h[2], a);                               \
        a = fdot2_(dec8<true >(W.y), I0.h[3], a);                               \
        a = fdot2_(dec8<false>(W.z), I1.h[0], a);                               \
        a = fdot2_(dec8<true >(W.z), I1.h[1], a);                               \
        a = fdot2_(dec8<false>(W.w), I1.h[2], a);                               \
        a = fdot2_(dec8<true >(W.w), I1.h[3], a);                               \
    } while (0)

    uint4 A0a, A0b, B0a, B0b;                 // half0 double-buffer (cross-step)
    float4 blA = make_float4(0.f, 0.f, 0.f, 0.f), blB = make_float4(0.f, 0.f, 0.f, 0.f);
    float  wxA = 0.0f, wxB = 0.0f;

    // prologue: prefetch step 0's half0 + bias + x-row
    {
        const int m0 = (int)s_X[T];
        const uint4* p0 = pack + (size_t)(m0 * 2) * 2048;
        A0a = p0[tid]; A0b = p0[1024 + tid];
        if (tid < H) {
            const float* bb = b_lin + m0 * H4 + tid;
            blA.x = bb[0]; blA.y = bb[H]; blA.z = bb[2 * H]; blA.w = bb[3 * H];
        }
        if (kh == 0) wxA = W_lin[(size_t)m0 * WF_STRIDE + c];
    }

    #define STEP(C0A, C0B, N0A, N0B, CBL, NBL, CWX, NWX)                        \
    {                                                                           \
        const int   mj  = (int)s_X[T + j];                                      \
        const float xj  = s_X[2 * T + j];                                       \
        const int   jn  = (j + 1 < T) ? (j + 1) : (T - 1);                      \
        const int   mjn = (int)s_X[T + jn];                                     \
        /* in-step: half1(j) weights */                                         \
        const uint4* p1 = pack + (size_t)(mj * 2 + 1) * 2048;                   \
        const uint4 h1a = p1[tid];                                              \
        const uint4 h1b = p1[1024 + tid];                                       \
        /* cross-step prefetch: half0(j+1) + bias + x-row */                    \
        const uint4* p0n = pack + (size_t)(mjn * 2) * 2048;                     \
        N0A = p0n[tid]; N0B = p0n[1024 + tid];                                  \
        if (tid < H) {                                                          \
            const float* bb = b_lin + mjn * H4 + tid;                           \
            NBL.x = bb[0]; NBL.y = bb[H]; NBL.z = bb[2 * H]; NBL.w = bb[3 * H]; \
        }                                                                       \
        if (kh == 0) NWX = W_lin[(size_t)mjn * WF_STRIDE + c];                  \
        /* matvec: k = h*64 + kh*32 + q*16 + r ; input half2 idx = k/2 */       \
        float a = 0.0f;                                                         \
        DOTU4(C0A, kh * 16);                                                    \
        DOTU4(C0B, kh * 16 + 8);                                                \
        DOTU4(h1a, 32 + kh * 16);                                               \
        DOTU4(h1b, 32 + kh * 16 + 8);                                           \
        a *= (1.0f / 4096.0f);                                                  \
        if (kh == 0) a = fmaf(xj, CWX, a);                                      \
        s_part[kh][c] = a;                                                      \
        __syncthreads();  /* B: partials ready */                               \
        if (tid < H) {                                                          \
            const int h = tid;                                                  \
            const float gi = s_part[0][h]       + s_part[1][h]       + CBL.x;   \
            const float gf = s_part[0][H + h]   + s_part[1][H + h]   + CBL.y;   \
            const float go = s_part[0][2*H + h] + s_part[1][2*H + h] + CBL.z;   \
            const float gc = s_part[0][3*H + h] + s_part[1][3*H + h] + CBL.w;   \
            const float c_cand = sigmoidf_(gf) * c_t + sigmoidf_(gi) * tanhf_(gc); \
            const float h_row  = sigmoidf_(go) * tanhf_(c_cand);                \
            s_ht[mj * H + h] = h_row;                                           \
            acc += c_cand;                                                      \
            cnt += 1.0f;                                                        \
            const float tj = s_X[j];                                            \
            const float tn = (j < T - 1) ? s_X[j + 1] : (tj + 1.0f);            \
            const bool boundary = (j == len - 1) || (tn != tj);                 \
            if (boundary) { c_t = acc / fmaxf(cnt, 1.0f); acc = 0.0f; cnt = 0.0f; } \
            /* produce next step's decayed input (fp16) */                      \
            const float dn  = s_X[3 * T + jn];                                  \
            const float dmn = fmaf(s_wdec[mjn], dn, s_bdec[mjn]);               \
            const float den = __expf(-fmaxf(0.0f, dmn));                        \
            const float hv  = (mjn == mj) ? h_row : s_ht[mjn * H + h];          \
            ((_Float16*)s_inp2)[h] = (_Float16)(den * hv);                      \
        }                                                                       \
        __syncthreads();  /* A: s_inp2 + h_t ready */                           \
    }

    int j = 0;
    while (j < len) {
        STEP(A0a, A0b, B0a, B0b, blA, blB, wxA, wxB); ++j;
        if (j >= len) break;
        STEP(B0a, B0b, A0a, A0b, blB, blA, wxB, wxA); ++j;
    }
    #undef STEP
    #undef DOTU4

    // ---- epilogue ----
    if (tid < H) s_ct[tid] = c_t;
    __syncthreads();

    float z0 = 0.0f, z1 = 0.0f;
    for (int i = tid; i < FEATS; i += NTH) {
        const float f = s_feats[i];
        const float2 w = *(const float2*)(W_out + 2 * i);
        z0 = fmaf(f, w.x, z0);
        z1 = fmaf(f, w.y, z1);
    }
    #pragma unroll
    for (int off = 32; off > 0; off >>= 1) {
        z0 += __shfl_down(z0, off, 64);
        z1 += __shfl_down(z1, off, 64);
    }
    const int wave = tid >> 6, lane = tid & 63;
    if (lane == 0) { s_red[2 * wave] = z0; s_red[2 * wave + 1] = z1; }
    __syncthreads();
    if (tid == 0) {
        float a0 = b_out[0], a1 = b_out[1];
        #pragma unroll
        for (int w = 0; w < 16; ++w) { a0 += s_red[2 * w]; a1 += s_red[2 * w + 1]; }
        const float mx = fmaxf(a0, a1);
        const float e0 = __expf(a0 - mx), e1 = __expf(a1 - mx);
        const float inv = 1.0f / (e0 + e1);
        out[2 * b]     = e0 * inv;
        out[2 * b + 1] = e1 * inv;
    }
}

// ---------------- fp32 fallback (no-workspace path) ----------------
#define NTHREADS 512
__global__ __launch_bounds__(NTHREADS)
void lstm_scan_kernel(const float* __restrict__ X,
                      const int* __restrict__ lengths,
                      const float* __restrict__ W_lin,
                      const float* __restrict__ b_lin,
                      const float* __restrict__ W_dec,
                      const float* __restrict__ b_dec,
                      const float* __restrict__ W_out,
                      const float* __restrict__ b_out,
                      float* __restrict__ out)
{
    __shared__ float s_feats[FEATS];
    __shared__ float s_inp[H];
    __shared__ float s_part[4][H4];
    __shared__ float s_X[4 * T];
    __shared__ float s_wdec[NF];
    __shared__ float s_bdec[NF];
    __shared__ float s_red[16];

    float* s_ct = s_feats;
    float* s_ht = s_feats + H;

    const int tid = threadIdx.x;
    const int b   = blockIdx.x;
    const int g4  = tid & 127;
    const int kq  = tid >> 7;

    const float* Xb = X + b * 4 * T;
    const int len = lengths[b];

    for (int i = tid; i < NF * H; i += NTHREADS) s_ht[i] = 0.0f;
    for (int i = tid; i < 4 * T; i += NTHREADS) s_X[i] = Xb[i];
    if (tid < NF) { s_wdec[tid] = W_dec[tid]; s_bdec[tid] = b_dec[tid]; }
    __syncthreads();

    float c_t = 0.0f, acc = 0.0f, cnt = 0.0f;

    for (int j = 0; j < len; ++j) {
        const int   mj = (int)s_X[T + j];
        const float xj = s_X[2 * T + j];
        const float* Wf = W_lin + mj * WF_STRIDE;

        float bl0, bl1, bl2, bl3;
        if (tid < H) {
            const float dj    = s_X[3 * T + j];
            const float dm    = fmaf(s_wdec[mj], dj, s_bdec[mj]);
            const float decay = __expf(-fmaxf(0.0f, dm));
            s_inp[tid] = decay * s_ht[mj * H + tid];
            const int m4 = mj * H4;
            bl0 = b_lin[m4 + tid];
            bl1 = b_lin[m4 + H + tid];
            bl2 = b_lin[m4 + 2 * H + tid];
            bl3 = b_lin[m4 + 3 * H + tid];
        }
        __syncthreads();

        float4 a4 = make_float4(0.0f, 0.0f, 0.0f, 0.0f);
        {
            const float*  wr  = Wf + (1 + kq * 32) * H4 + 4 * g4;
            const float4* ivp = (const float4*)(s_inp + kq * 32);
            #pragma unroll
            for (int cc = 0; cc < 8; ++cc) {
                const float4 v = ivp[cc];
                const float* wrc = wr + (4 * cc) * H4;
                const float4 w0 = *(const float4*)(wrc);
                const float4 w1 = *(const float4*)(wrc + H4);
                const float4 w2 = *(const float4*)(wrc + 2 * H4);
                const float4 w3 = *(const float4*)(wrc + 3 * H4);
                a4.x = fmaf(v.x, w0.x, a4.x); a4.y = fmaf(v.x, w0.y, a4.y);
                a4.z = fmaf(v.x, w0.z, a4.z); a4.w = fmaf(v.x, w0.w, a4.w);
                a4.x = fmaf(v.y, w1.x, a4.x); a4.y = fmaf(v.y, w1.y, a4.y);
                a4.z = fmaf(v.y, w1.z, a4.z); a4.w = fmaf(v.y, w1.w, a4.w);
                a4.x = fmaf(v.z, w2.x, a4.x); a4.y = fmaf(v.z, w2.y, a4.y);
                a4.z = fmaf(v.z, w2.z, a4.z); a4.w = fmaf(v.z, w2.w, a4.w);
                a4.x = fmaf(v.w, w3.x, a4.x); a4.y = fmaf(v.w, w3.y, a4.y);
                a4.z = fmaf(v.w, w3.z, a4.z); a4.w = fmaf(v.w, w3.w, a4.w);
            }
        }
        if (kq == 0) {
            const float4 w = *(const float4*)(Wf + 4 * g4);
            a4.x = fmaf(xj, w.x, a4.x); a4.y = fmaf(xj, w.y, a4.y);
            a4.z = fmaf(xj, w.z, a4.z); a4.w = fmaf(xj, w.w, a4.w);
        }
        *(float4*)(&s_part[kq][4 * g4]) = a4;
        __syncthreads();

        if (tid < H) {
            const int h = tid;
            const float gi = s_part[0][h]         + s_part[1][h]         + s_part[2][h]         + s_part[3][h]         + bl0;
            const float gf = s_part[0][H + h]     + s_part[1][H + h]     + s_part[2][H + h]     + s_part[3][H + h]     + bl1;
            const float go = s_part[0][2*H + h]   + s_part[1][2*H + h]   + s_part[2][2*H + h]   + s_part[3][2*H + h]   + bl2;
            const float gc = s_part[0][3*H + h]   + s_part[1][3*H + h]   + s_part[2][3*H + h]   + s_part[3][3*H + h]   + bl3;

            const float c_cand = sigmoidf_(gf) * c_t + sigmoidf_(gi) * tanhf_(gc);
            const float h_row  = sigmoidf_(go) * tanhf_(c_cand);
            s_ht[mj * H + h] = h_row;
            acc += c_cand;
            cnt += 1.0f;

            const float tj = s_X[j];
            const float tn = (j < T - 1) ? s_X[j + 1] : (tj + 1.0f);
            const bool boundary = (j == len - 1) || (tn != tj);
            if (boundary) { c_t = acc / fmaxf(cnt, 1.0f); acc = 0.0f; cnt = 0.0f; }
        }
        __syncthreads();
    }

    if (tid < H) s_ct[tid] = c_t;
    __syncthreads();

    float z0 = 0.0f, z1 = 0.0f;
    for (int i = tid; i < FEATS; i += NTHREADS) {
        const float f = s_feats[i];
        const float2 w = *(const float2*)(W_out + 2 * i);
        z0 = fmaf(f, w.x, z0);
        z1 = fmaf(f, w.y, z1);
    }
    #pragma unroll
    for (int off = 32; off > 0; off >>= 1) {
        z0 += __shfl_down(z0, off, 64);
        z1 += __shfl_down(z1, off, 64);
    }
    const int wave = tid >> 6, lane = tid & 63;
    if (lane == 0) { s_red[2 * wave] = z0; s_red[2 * wave + 1] = z1; }
    __syncthreads();
    if (tid == 0) {
        float a0 = b_out[0], a1 = b_out[1];
        #pragma unroll
        for (int w = 0; w < 8; ++w) { a0 += s_red[2 * w]; a1 += s_red[2 * w + 1]; }
        const float mx = fmaxf(a0, a1);
        const float e0 = __expf(a0 - mx), e1 = __expf(a1 - mx);
        const float inv = 1.0f / (e0 + e1);
        out[2 * b]     = e0 * inv;
        out[2 * b + 1] = e1 * inv;
    }
}

extern "C" void kernel_launch(void* const* d_in, const int* in_sizes, int n_in,
                              void* d_out, int out_size, void* d_ws, size_t ws_size,
                              hipStream_t stream) {
    const float* X      = (const float*)d_in[0];
    const int*   lens   = (const int*)d_in[1];
    const float* W_lin  = (const float*)d_in[2];
    const float* b_lin  = (const float*)d_in[3];
    const float* W_dec  = (const float*)d_in[4];
    const float* b_dec  = (const float*)d_in[5];
    const float* W_out  = (const float*)d_in[6];
    const float* b_out  = (const float*)d_in[7];
    float* out = (float*)d_out;

    if (ws_size >= PACK8_BYTES) {
        uint4* pack = (uint4*)d_ws;
        hipLaunchKernelGGL(repack8_kernel, dim3(PACK8_U4 / 256), dim3(256), 0, stream,
                           W_lin, pack);
        hipLaunchKernelGGL(lstm_scan_fp8_kernel, dim3(BATCH), dim3(NTH), 0, stream,
                           X, lens, W_lin, b_lin, W_dec, b_dec, W_out, b_out, pack, out);
    } else {
        hipLaunchKernelGGL(lstm_scan_kernel, dim3(BATCH), dim3(NTHREADS), 0, stream,
                           X, lens, W_lin, b_lin, W_dec, b_dec, W_out, b_out, out);
    }
}